// Round 4
// baseline (416.322 us; speedup 1.0000x reference)
//
#include <hip/hip_runtime.h>
#include <hip/hip_bf16.h>
#include <math.h>

#define LQN 1024
#define LKN 1024
#define NB 16
#define DM 160
#define NHEADS 8
#define HDIM 20
#define PSTR 88  // P-tile LDS row stride (shorts): 16B-aligned, conflict-light

typedef __attribute__((ext_vector_type(8))) short bf16x8;
typedef __attribute__((ext_vector_type(4))) float f32x4;

__device__ __forceinline__ float bf2f(unsigned short h) {
  union { unsigned int u; float f; } c; c.u = ((unsigned int)h) << 16; return c.f;
}
__device__ __forceinline__ unsigned short f2bf(float f) {
  union { float f; unsigned int u; } c; c.f = f;
  unsigned int lsb = (c.u >> 16) & 1u;
  unsigned int r = c.u + 0x7fffu + lsb;
  return (unsigned short)(r >> 16);
}
__device__ __forceinline__ unsigned int cvtpk(float a, float b) {
  unsigned int r;
  asm("v_cvt_pk_bf16_f32 %0, %1, %2" : "=v"(r) : "v"(a), "v"(b));
  return r;
}

// ---- DPP 16-lane all-reduce (no LDS path) ----
template <int CTRL>
__device__ __forceinline__ float dpp_mov(float x) {
  union { float f; int i; } c; c.f = x;
  c.i = __builtin_amdgcn_update_dpp(c.i, c.i, CTRL, 0xf, 0xf, true);
  return c.f;
}
__device__ __forceinline__ float red16_max(float x) {
  x = fmaxf(x, dpp_mov<0xB1>(x));   // quad_perm [1,0,3,2]
  x = fmaxf(x, dpp_mov<0x4E>(x));   // quad_perm [2,3,0,1]
  x = fmaxf(x, dpp_mov<0x141>(x));  // row_half_mirror
  x = fmaxf(x, dpp_mov<0x140>(x));  // row_mirror
  return x;
}
__device__ __forceinline__ float red16_add(float x) {
  x += dpp_mov<0xB1>(x);
  x += dpp_mov<0x4E>(x);
  x += dpp_mov<0x141>(x);
  x += dpp_mov<0x140>(x);
  return x;
}

// ---------------- zero-fill (pad regions), uint4 stores ----------------
__global__ void zero_kernel(uint4* __restrict__ p, int n4) {
  int i = blockIdx.x * 256 + threadIdx.x;
  if (i < n4) p[i] = make_uint4(0, 0, 0, 0);
}

// ---------------- fused f32 -> bf16 weight convert (8 segments) ----------
struct CvtArgs {
  const float* src[8];
  int cum[9];
};
__global__ void cvt8_kernel(CvtArgs a, unsigned short* __restrict__ dst) {
  int i = blockIdx.x * 256 + threadIdx.x;
  if (i >= 409600) return;
  int s = 0;
#pragma unroll
  for (int t = 0; t < 7; ++t) s += (i >= a.cum[t + 1]) ? 1 : 0;
  dst[i] = f2bf(a.src[s][i - a.cum[s]]);
}

// ---------------- LayerNorm over D=160, one wave per row ----------------
__global__ void ln_kernel(const float* __restrict__ x,
                          const float* __restrict__ g,
                          const float* __restrict__ b,
                          unsigned short* __restrict__ y, int rows) {
  int row = blockIdx.x * 4 + (threadIdx.x >> 6);
  int lane = threadIdx.x & 63;
  const float* xr = x + (size_t)row * DM;
  float a0 = xr[lane];
  float a1 = xr[lane + 64];
  float a2 = (lane < 32) ? xr[lane + 128] : 0.0f;
  float s = a0 + a1 + a2;
#pragma unroll
  for (int m = 1; m < 64; m <<= 1) s += __shfl_xor(s, m);
  float mean = s * (1.0f / DM);
  float d0 = a0 - mean, d1 = a1 - mean, d2 = a2 - mean;
  float vs = d0 * d0 + d1 * d1 + ((lane < 32) ? d2 * d2 : 0.0f);
#pragma unroll
  for (int m = 1; m < 64; m <<= 1) vs += __shfl_xor(vs, m);
  float rstd = rsqrtf(vs * (1.0f / DM) + 1e-5f);
  unsigned short* yr = y + (size_t)row * DM;
  yr[lane]      = f2bf(d0 * rstd * g[lane]      + b[lane]);
  yr[lane + 64] = f2bf(d1 * rstd * g[lane + 64] + b[lane + 64]);
  if (lane < 32)
    yr[lane + 128] = f2bf(d2 * rstd * g[lane + 128] + b[lane + 128]);
}

// ---------------- GEMM: out[M,N] = A[M,K] @ W[N,K]^T + bias ----------------
// EPI 0: bias->bf16  1: bias+res->f32  2: bias+gelu->bf16
// PAD 1: out is head-padded bf16 [row][256], col c -> (c/20)*32 + c%20
template <int EPI, int PAD>
__global__ void gemm_kernel(const unsigned short* __restrict__ A,
                            const unsigned short* __restrict__ W,
                            const float* __restrict__ bias,
                            const float* __restrict__ res,
                            void* __restrict__ outp, int N, int K) {
  int lane = threadIdx.x & 63;
  int wid = threadIdx.x >> 6;
  int wr = wid >> 1, wc = wid & 1;
  int r0 = blockIdx.x * 64 + wr * 32;
  int c0 = blockIdx.y * 64 + wc * 32;
  if (c0 >= N) return;
  int lr = lane & 15;
  int ko = (lane >> 4) * 8;
  const unsigned short* Ap0 = A + (size_t)(r0 + lr) * K + ko;
  const unsigned short* Ap1 = Ap0 + (size_t)16 * K;
  const unsigned short* Wp0 = W + (size_t)(c0 + lr) * K + ko;
  const unsigned short* Wp1 = Wp0 + (size_t)16 * K;
  f32x4 acc00 = {0, 0, 0, 0}, acc01 = {0, 0, 0, 0};
  f32x4 acc10 = {0, 0, 0, 0}, acc11 = {0, 0, 0, 0};
  for (int k = 0; k < K; k += 32) {
    bf16x8 a0 = *(const bf16x8*)(Ap0 + k);
    bf16x8 a1 = *(const bf16x8*)(Ap1 + k);
    bf16x8 b0 = *(const bf16x8*)(Wp0 + k);
    bf16x8 b1 = *(const bf16x8*)(Wp1 + k);
    acc00 = __builtin_amdgcn_mfma_f32_16x16x32_bf16(a0, b0, acc00, 0, 0, 0);
    acc01 = __builtin_amdgcn_mfma_f32_16x16x32_bf16(a0, b1, acc01, 0, 0, 0);
    acc10 = __builtin_amdgcn_mfma_f32_16x16x32_bf16(a1, b0, acc10, 0, 0, 0);
    acc11 = __builtin_amdgcn_mfma_f32_16x16x32_bf16(a1, b1, acc11, 0, 0, 0);
  }
  int cA = c0 + lr, cB = c0 + 16 + lr;
  float bc0 = bias[cA];
  float bc1 = bias[cB];
  int pcA = (cA / 20) * 32 + cA % 20;
  int pcB = (cB / 20) * 32 + cB % 20;
  int rb = (lane >> 4) * 4;
#pragma unroll
  for (int i = 0; i < 2; ++i) {
    f32x4 aA = i ? acc10 : acc00;
    f32x4 aB = i ? acc11 : acc01;
#pragma unroll
    for (int r = 0; r < 4; ++r) {
      int row = r0 + i * 16 + rb + r;
      float v0 = aA[r] + bc0;
      float v1 = aB[r] + bc1;
      if (EPI == 2) {
        v0 = 0.5f * v0 * (1.0f + erff(v0 * 0.70710678118654752f));
        v1 = 0.5f * v1 * (1.0f + erff(v1 * 0.70710678118654752f));
      }
      if (EPI == 1) {
        float* out = (float*)outp;
        out[(size_t)row * N + cA] = v0 + res[(size_t)row * N + cA];
        out[(size_t)row * N + cB] = v1 + res[(size_t)row * N + cB];
      } else if (PAD) {
        unsigned short* out = (unsigned short*)outp;
        out[(size_t)row * 256 + pcA] = f2bf(v0);
        out[(size_t)row * 256 + pcB] = f2bf(v1);
      } else {
        unsigned short* out = (unsigned short*)outp;
        out[(size_t)row * N + cA] = f2bf(v0);
        out[(size_t)row * N + cB] = f2bf(v1);
      }
    }
  }
}

// ---- GEMM, TRANSPOSED head-padded output: outT[(b*256 + pc)*1024 + token] ----
__global__ void gemm_t_kernel(const unsigned short* __restrict__ A,
                              const unsigned short* __restrict__ W,
                              const float* __restrict__ bias,
                              unsigned short* __restrict__ outT, int N, int K) {
  int lane = threadIdx.x & 63;
  int wid = threadIdx.x >> 6;
  int wr = wid >> 1, wc = wid & 1;
  int r0 = blockIdx.x * 64 + wr * 32;
  int c0 = blockIdx.y * 64 + wc * 32;
  if (c0 >= N) return;
  int lr = lane & 15;
  int ko = (lane >> 4) * 8;
  const unsigned short* Ap0 = A + (size_t)(r0 + lr) * K + ko;
  const unsigned short* Ap1 = Ap0 + (size_t)16 * K;
  const unsigned short* Wp0 = W + (size_t)(c0 + lr) * K + ko;
  const unsigned short* Wp1 = Wp0 + (size_t)16 * K;
  f32x4 acc00 = {0, 0, 0, 0}, acc01 = {0, 0, 0, 0};
  f32x4 acc10 = {0, 0, 0, 0}, acc11 = {0, 0, 0, 0};
  for (int k = 0; k < K; k += 32) {
    bf16x8 a0 = *(const bf16x8*)(Ap0 + k);
    bf16x8 a1 = *(const bf16x8*)(Ap1 + k);
    bf16x8 b0 = *(const bf16x8*)(Wp0 + k);
    bf16x8 b1 = *(const bf16x8*)(Wp1 + k);
    acc00 = __builtin_amdgcn_mfma_f32_16x16x32_bf16(a0, b0, acc00, 0, 0, 0);
    acc01 = __builtin_amdgcn_mfma_f32_16x16x32_bf16(a0, b1, acc01, 0, 0, 0);
    acc10 = __builtin_amdgcn_mfma_f32_16x16x32_bf16(a1, b0, acc10, 0, 0, 0);
    acc11 = __builtin_amdgcn_mfma_f32_16x16x32_bf16(a1, b1, acc11, 0, 0, 0);
  }
  int cA = c0 + lr, cB = c0 + 16 + lr;
  float bc0 = bias[cA];
  float bc1 = bias[cB];
  int pcA = (cA / 20) * 32 + cA % 20;
  int pcB = (cB / 20) * 32 + cB % 20;
  int rb = (lane >> 4) * 4;
  int b = r0 >> 10;
  int tok0 = (r0 & 1023) + rb;
  size_t colA = ((size_t)b * 256 + pcA) * 1024;
  size_t colB = ((size_t)b * 256 + pcB) * 1024;
#pragma unroll
  for (int i = 0; i < 2; ++i) {
    f32x4 aA = i ? acc10 : acc00;
    f32x4 aB = i ? acc11 : acc01;
    int t0 = tok0 + i * 16;
    *(unsigned int*)(outT + colA + t0)     = cvtpk(aA[0] + bc0, aA[1] + bc0);
    *(unsigned int*)(outT + colA + t0 + 2) = cvtpk(aA[2] + bc0, aA[3] + bc0);
    *(unsigned int*)(outT + colB + t0)     = cvtpk(aB[0] + bc1, aB[1] + bc1);
    *(unsigned int*)(outT + colB + t0 + 2) = cvtpk(aB[2] + bc1, aB[3] + bc1);
  }
}

// ---------------- flash attention, head-padded inputs, KVBLK=64 ------------
// Qp,Kp: [b*1024+tok][256] bf16 (h*32+d). vTp: [(b*256 + h*32+d)][1024] bf16.
// grid: (LQ/64, B*NH); block 256 = 4 waves, 16 q-rows/wave. No barriers.
__global__ void attn_kernel(const unsigned short* __restrict__ Qp,
                            const unsigned short* __restrict__ Kp,
                            const unsigned short* __restrict__ vTp,
                            unsigned short* __restrict__ O,
                            const float* __restrict__ tau_ptr,
                            float base_scale) {
  __shared__ unsigned short plds[4][16 * PSTR];
  int lane = threadIdx.x & 63;
  int wid = threadIdx.x >> 6;
  int bh = blockIdx.y;
  int b = bh >> 3, h = bh & 7;
  int q0 = blockIdx.x * 64 + wid * 16;
  float sc = base_scale;
  if (tau_ptr) {
    float lt = tau_ptr[0];
    float sp = (lt > 20.0f) ? lt : log1pf(expf(lt));
    sc /= fminf(sp + 0.5f, 2.0f);
  }
  float scale = sc * 1.4426950408889634f;  // log2 domain
  int lr = lane & 15;
  int g = lane >> 4;
  int ko = g * 8;
  int rb = g * 4;
  const size_t tb = (size_t)b * LQN;
  bf16x8 aq = *(const bf16x8*)(Qp + (tb + q0 + lr) * 256 + h * 32 + ko);
  const unsigned short* kr0 = Kp + (tb + lr) * 256 + h * 32 + ko;
  const unsigned short* kr = kr0;
  const unsigned short* vr0 = vTp + ((size_t)b * 256 + h * 32 + lr) * LKN + ko;
  const unsigned short* vr1 = vr0 + (size_t)16 * LKN;
  unsigned short* pwr = plds[wid] + rb * PSTR + lr;
  const unsigned short* pra = plds[wid] + lr * PSTR + ko;
  f32x4 o0 = {0, 0, 0, 0}, o1 = {0, 0, 0, 0};
  float mrow[4], lsum[4];
#pragma unroll
  for (int r = 0; r < 4; ++r) { mrow[r] = -3.0e38f; lsum[r] = 0.0f; }
  const f32x4 zero = {0, 0, 0, 0};
  bf16x8 ck0 = *(const bf16x8*)(kr);
  bf16x8 ck1 = *(const bf16x8*)(kr + 16 * 256);
  bf16x8 ck2 = *(const bf16x8*)(kr + 32 * 256);
  bf16x8 ck3 = *(const bf16x8*)(kr + 48 * 256);
  for (int kt = 0; kt < LKN; kt += 64) {
    f32x4 s0 = __builtin_amdgcn_mfma_f32_16x16x32_bf16(aq, ck0, zero, 0, 0, 0);
    f32x4 s1 = __builtin_amdgcn_mfma_f32_16x16x32_bf16(aq, ck1, zero, 0, 0, 0);
    f32x4 s2 = __builtin_amdgcn_mfma_f32_16x16x32_bf16(aq, ck2, zero, 0, 0, 0);
    f32x4 s3 = __builtin_amdgcn_mfma_f32_16x16x32_bf16(aq, ck3, zero, 0, 0, 0);
    // prefetch next K tile (wrap on last iter to stay in-bounds)
    kr = (kt + 64 < LKN) ? kr + 64 * 256 : kr0;
    ck0 = *(const bf16x8*)(kr);
    ck1 = *(const bf16x8*)(kr + 16 * 256);
    ck2 = *(const bf16x8*)(kr + 32 * 256);
    ck3 = *(const bf16x8*)(kr + 48 * 256);
    // V tile for this kt (issued early; consumed after softmax)
    bf16x8 vb00 = *(const bf16x8*)(vr0 + kt + ko);
    bf16x8 vb01 = *(const bf16x8*)(vr0 + kt + 32 + ko);
    bf16x8 vb10 = *(const bf16x8*)(vr1 + kt + ko);
    bf16x8 vb11 = *(const bf16x8*)(vr1 + kt + 32 + ko);
#pragma unroll
    for (int r = 0; r < 4; ++r) {
      float tm = fmaxf(fmaxf(s0[r], s1[r]), fmaxf(s2[r], s3[r]));
      tm = red16_max(tm);
      float mnew = fmaxf(mrow[r], tm * scale);
      float fac = exp2f(mrow[r] - mnew);
      float p0 = exp2f(fmaf(s0[r], scale, -mnew));
      float p1 = exp2f(fmaf(s1[r], scale, -mnew));
      float p2 = exp2f(fmaf(s2[r], scale, -mnew));
      float p3 = exp2f(fmaf(s3[r], scale, -mnew));
      float rs = red16_add((p0 + p1) + (p2 + p3));
      lsum[r] = lsum[r] * fac + rs;
      o0[r] *= fac; o1[r] *= fac;
      mrow[r] = mnew;
      unsigned int pkA = cvtpk(p0, p1), pkB = cvtpk(p2, p3);
      pwr[r * PSTR]      = (unsigned short)pkA;
      pwr[r * PSTR + 16] = (unsigned short)(pkA >> 16);
      pwr[r * PSTR + 32] = (unsigned short)pkB;
      pwr[r * PSTR + 48] = (unsigned short)(pkB >> 16);
    }
    bf16x8 pa0 = *(const bf16x8*)(pra);
    bf16x8 pa1 = *(const bf16x8*)(pra + 32);
    o0 = __builtin_amdgcn_mfma_f32_16x16x32_bf16(pa0, vb00, o0, 0, 0, 0);
    o0 = __builtin_amdgcn_mfma_f32_16x16x32_bf16(pa1, vb01, o0, 0, 0, 0);
    o1 = __builtin_amdgcn_mfma_f32_16x16x32_bf16(pa0, vb10, o1, 0, 0, 0);
    o1 = __builtin_amdgcn_mfma_f32_16x16x32_bf16(pa1, vb11, o1, 0, 0, 0);
  }
  unsigned short* ob = O + (tb + q0) * DM + h * HDIM;
#pragma unroll
  for (int r = 0; r < 4; ++r) {
    int qr = rb + r;
    float inv = 1.0f / lsum[r];
    ob[(size_t)qr * DM + lr] = f2bf(o0[r] * inv);
    if (lr < 4) ob[(size_t)qr * DM + 16 + lr] = f2bf(o1[r] * inv);
  }
}

extern "C" void kernel_launch(void* const* d_in, const int* in_sizes, int n_in,
                              void* d_out, int out_size, void* d_ws, size_t ws_size,
                              hipStream_t stream) {
  (void)in_sizes; (void)n_in; (void)out_size; (void)ws_size;
  const float* q        = (const float*)d_in[0];
  const float* kv       = (const float*)d_in[1];
  const float* ln1_g    = (const float*)d_in[2];
  const float* ln1_b    = (const float*)d_in[3];
  const float* sa_in_w  = (const float*)d_in[4];
  const float* sa_in_b  = (const float*)d_in[5];
  const float* sa_out_w = (const float*)d_in[6];
  const float* sa_out_b = (const float*)d_in[7];
  const float* ln2_g    = (const float*)d_in[8];
  const float* ln2_b    = (const float*)d_in[9];
  const float* lnkv_g   = (const float*)d_in[10];
  const float* lnkv_b   = (const float*)d_in[11];
  const float* ca_qw    = (const float*)d_in[12];
  const float* ca_qb    = (const float*)d_in[13];
  const float* ca_kw    = (const float*)d_in[14];
  const float* ca_kb    = (const float*)d_in[15];
  const float* ca_vw    = (const float*)d_in[16];
  const float* ca_vb    = (const float*)d_in[17];
  const float* ca_ow    = (const float*)d_in[18];
  const float* ca_ob    = (const float*)d_in[19];
  const float* log_tau  = (const float*)d_in[20];
  const float* lnf_g    = (const float*)d_in[21];
  const float* lnf_b    = (const float*)d_in[22];
  const float* w1       = (const float*)d_in[23];
  const float* b1       = (const float*)d_in[24];
  const float* w2       = (const float*)d_in[25];
  const float* b2       = (const float*)d_in[26];

  const int M = NB * LQN;  // 16384 rows
  char* ws = (char*)d_ws;
  // layout (byte offsets), total 62,914,560:
  //   wb   @ 0           819,200     bf16 weights
  //   qn   @ 1,048,576   5,242,880   bf16 [16384,160] (all LN outputs)
  //   sqp  @ 6,291,456   8,388,608   bf16 [16384,256] padded Q (reused: caq)
  //   skp  @ 14,680,064  8,388,608   bf16 [16384,256] padded K (reused: cak)
  //   vTp  @ 23,068,672  8,388,608   bf16 [4096,1024] padded V^T (reused: cav)
  //   attn @ 31,457,280  5,242,880   bf16 [16384,160]
  //   kvn  @ 36,700,160  5,242,880   bf16 [16384,160]
  //   q1   @ 41,943,040  10,485,760  f32
  //   q2   @ 52,428,800  10,485,760  f32
  //   hbuf @ 6,291,456   20,971,520  bf16 [16384,640] (FFN phase; overlaps
  //                                  sqp/skp/vTp which are dead by then)
  unsigned short* wb   = (unsigned short*)(ws);
  unsigned short* qn   = (unsigned short*)(ws + 1048576);
  unsigned short* sqp  = (unsigned short*)(ws + 6291456);
  unsigned short* skp  = (unsigned short*)(ws + 14680064);
  unsigned short* vTp  = (unsigned short*)(ws + 23068672);
  unsigned short* attn = (unsigned short*)(ws + 31457280);
  unsigned short* kvn  = (unsigned short*)(ws + 36700160);
  float*          q1   = (float*)(ws + 41943040);
  float*          q2   = (float*)(ws + 52428800);
  unsigned short* hbuf = (unsigned short*)(ws + 6291456);

  unsigned short* b_sa_in  = wb;            // 76800
  unsigned short* b_sa_out = wb + 76800;    // 25600
  unsigned short* b_ca_q   = wb + 102400;   // 25600
  unsigned short* b_ca_k   = wb + 128000;   // 25600
  unsigned short* b_ca_v   = wb + 153600;   // 25600
  unsigned short* b_ca_o   = wb + 179200;   // 25600
  unsigned short* b_w1     = wb + 204800;   // 102400
  unsigned short* b_w2     = wb + 307200;   // 102400

  dim3 blk(256);
  const float isq = 0.22360679774997896f;  // 1/sqrt(20)

  // --- zero the padded buffers (pads must be 0 for MFMA) ---
  zero_kernel<<<dim3(6144), blk, 0, stream>>>((uint4*)(ws + 6291456), 1572864);

  // --- weight conversion, one launch ---
  CvtArgs ca;
  ca.src[0] = sa_in_w;  ca.src[1] = sa_out_w; ca.src[2] = ca_qw; ca.src[3] = ca_kw;
  ca.src[4] = ca_vw;    ca.src[5] = ca_ow;    ca.src[6] = w1;    ca.src[7] = w2;
  int cum[9] = {0, 76800, 102400, 128000, 153600, 179200, 204800, 307200, 409600};
  for (int i = 0; i < 9; ++i) ca.cum[i] = cum[i];
  cvt8_kernel<<<dim3(1600), blk, 0, stream>>>(ca, wb);

  // --- self attention block ---
  ln_kernel<<<dim3(M / 4), blk, 0, stream>>>(q, ln1_g, ln1_b, qn, M);
  gemm_kernel<0, 1><<<dim3(M / 64, 3), blk, 0, stream>>>(qn, b_sa_in, sa_in_b, nullptr, sqp, 160, 160);
  gemm_kernel<0, 1><<<dim3(M / 64, 3), blk, 0, stream>>>(qn, b_sa_in + 160 * 160, sa_in_b + 160, nullptr, skp, 160, 160);
  gemm_t_kernel<<<dim3(M / 64, 3), blk, 0, stream>>>(qn, b_sa_in + 320 * 160, sa_in_b + 320, vTp, 160, 160);
  attn_kernel<<<dim3(LQN / 64, NB * NHEADS), blk, 0, stream>>>(sqp, skp, vTp, attn, nullptr, isq);
  gemm_kernel<1, 0><<<dim3(M / 64, 3), blk, 0, stream>>>(attn, b_sa_out, sa_out_b, q, q1, 160, 160);

  // --- cross attention block ---
  ln_kernel<<<dim3(M / 4), blk, 0, stream>>>(q1, ln2_g, ln2_b, qn, M);
  ln_kernel<<<dim3(M / 4), blk, 0, stream>>>(kv, lnkv_g, lnkv_b, kvn, M);
  gemm_kernel<0, 1><<<dim3(M / 64, 3), blk, 0, stream>>>(qn, b_ca_q, ca_qb, nullptr, sqp, 160, 160);
  gemm_kernel<0, 1><<<dim3(M / 64, 3), blk, 0, stream>>>(kvn, b_ca_k, ca_kb, nullptr, skp, 160, 160);
  gemm_t_kernel<<<dim3(M / 64, 3), blk, 0, stream>>>(kvn, b_ca_v, ca_vb, vTp, 160, 160);
  attn_kernel<<<dim3(LQN / 64, NB * NHEADS), blk, 0, stream>>>(sqp, skp, vTp, attn, log_tau, isq);
  gemm_kernel<1, 0><<<dim3(M / 64, 3), blk, 0, stream>>>(attn, b_ca_o, ca_ob, q1, q2, 160, 160);

  // --- FFN ---
  ln_kernel<<<dim3(M / 4), blk, 0, stream>>>(q2, lnf_g, lnf_b, qn, M);
  gemm_kernel<2, 0><<<dim3(M / 64, 10), blk, 0, stream>>>(qn, b_w1, b1, nullptr, hbuf, 640, 160);
  gemm_kernel<1, 0><<<dim3(M / 64, 3), blk, 0, stream>>>(hbuf, b_w2, b2, q2, (float*)d_out, 160, 640);
}

// Round 5
// 369.494 us; speedup vs baseline: 1.1267x; 1.1267x over previous
//
#include <hip/hip_runtime.h>
#include <hip/hip_bf16.h>
#include <math.h>

#define LQN 1024
#define LKN 1024
#define NB 16
#define DM 160
#define NHEADS 8
#define HDIM 20
#define PSTR 88  // P-tile LDS row stride (shorts)

typedef __attribute__((ext_vector_type(8))) short bf16x8;
typedef __attribute__((ext_vector_type(4))) float f32x4;

__device__ __forceinline__ float bf2f(unsigned short h) {
  union { unsigned int u; float f; } c; c.u = ((unsigned int)h) << 16; return c.f;
}
__device__ __forceinline__ unsigned short f2bf(float f) {
  union { float f; unsigned int u; } c; c.f = f;
  unsigned int lsb = (c.u >> 16) & 1u;
  unsigned int r = c.u + 0x7fffu + lsb;
  return (unsigned short)(r >> 16);
}
__device__ __forceinline__ unsigned int cvtpk(float a, float b) {
  unsigned int r;
  asm("v_cvt_pk_bf16_f32 %0, %1, %2" : "=v"(r) : "v"(a), "v"(b));
  return r;
}
// raw v_exp_f32 (2^x). HW flushes very-negative to 0 — exactly what we need.
__device__ __forceinline__ float ex2(float x) { return __builtin_amdgcn_exp2f(x); }

// ---- DPP 16-lane all-reduce (no LDS path) ----
template <int CTRL>
__device__ __forceinline__ float dpp_mov(float x) {
  union { float f; int i; } c; c.f = x;
  c.i = __builtin_amdgcn_update_dpp(c.i, c.i, CTRL, 0xf, 0xf, true);
  return c.f;
}
__device__ __forceinline__ float red16_max(float x) {
  x = fmaxf(x, dpp_mov<0xB1>(x));
  x = fmaxf(x, dpp_mov<0x4E>(x));
  x = fmaxf(x, dpp_mov<0x141>(x));
  x = fmaxf(x, dpp_mov<0x140>(x));
  return x;
}
__device__ __forceinline__ float red16_add(float x) {
  x += dpp_mov<0xB1>(x);
  x += dpp_mov<0x4E>(x);
  x += dpp_mov<0x141>(x);
  x += dpp_mov<0x140>(x);
  return x;
}

// ---------------- zero-fill (pad regions) ----------------
__global__ void zero_kernel(uint4* __restrict__ p, int n4) {
  int i = blockIdx.x * 256 + threadIdx.x;
  if (i < n4) p[i] = make_uint4(0, 0, 0, 0);
}

// ---------------- fused f32 -> bf16 weight convert ----------
struct CvtArgs {
  const float* src[8];
  int cum[9];
};
__global__ void cvt8_kernel(CvtArgs a, unsigned short* __restrict__ dst) {
  int i = blockIdx.x * 256 + threadIdx.x;
  if (i >= 409600) return;
  int s = 0;
#pragma unroll
  for (int t = 0; t < 7; ++t) s += (i >= a.cum[t + 1]) ? 1 : 0;
  dst[i] = f2bf(a.src[s][i - a.cum[s]]);
}

// ---------------- LayerNorm over D=160, one wave per row ----------------
__global__ void ln_kernel(const float* __restrict__ x,
                          const float* __restrict__ g,
                          const float* __restrict__ b,
                          unsigned short* __restrict__ y, int rows) {
  int row = blockIdx.x * 4 + (threadIdx.x >> 6);
  int lane = threadIdx.x & 63;
  const float* xr = x + (size_t)row * DM;
  float a0 = xr[lane];
  float a1 = xr[lane + 64];
  float a2 = (lane < 32) ? xr[lane + 128] : 0.0f;
  float s = a0 + a1 + a2;
#pragma unroll
  for (int m = 1; m < 64; m <<= 1) s += __shfl_xor(s, m);
  float mean = s * (1.0f / DM);
  float d0 = a0 - mean, d1 = a1 - mean, d2 = a2 - mean;
  float vs = d0 * d0 + d1 * d1 + ((lane < 32) ? d2 * d2 : 0.0f);
#pragma unroll
  for (int m = 1; m < 64; m <<= 1) vs += __shfl_xor(vs, m);
  float rstd = rsqrtf(vs * (1.0f / DM) + 1e-5f);
  unsigned short* yr = y + (size_t)row * DM;
  yr[lane]      = f2bf(d0 * rstd * g[lane]      + b[lane]);
  yr[lane + 64] = f2bf(d1 * rstd * g[lane + 64] + b[lane + 64]);
  if (lane < 32)
    yr[lane + 128] = f2bf(d2 * rstd * g[lane + 128] + b[lane + 128]);
}

// ============ fused QKV projection (N=160, K=160) ============
// grid (M/64, 9): y/3 = 0:Q(padded row-major) 1:K(padded) 2:V(transposed+
// token-permuted). Q uses Aq, K/V use Akv.
// padded col: pc = (c/20)*32 + c%20; row layout [row][256].
// V^T: outT[(b*256 + pc)*1024 + (tok&~31) + 2*(tok&15) + ((tok>>4)&1)]
__global__ void qkv_kernel(const unsigned short* __restrict__ Aq,
                           const unsigned short* __restrict__ Akv,
                           const unsigned short* __restrict__ Wq,
                           const unsigned short* __restrict__ Wk,
                           const unsigned short* __restrict__ Wv,
                           const float* __restrict__ bq,
                           const float* __restrict__ bk,
                           const float* __restrict__ bv,
                           unsigned short* __restrict__ Qp,
                           unsigned short* __restrict__ Kp,
                           unsigned short* __restrict__ vTp) {
  int which = blockIdx.y / 3;
  int yt = blockIdx.y % 3;
  const unsigned short* A = (which == 0) ? Aq : Akv;
  const unsigned short* W = (which == 0) ? Wq : (which == 1 ? Wk : Wv);
  const float* bias = (which == 0) ? bq : (which == 1 ? bk : bv);
  int lane = threadIdx.x & 63;
  int wid = threadIdx.x >> 6;
  int wr = wid >> 1, wc = wid & 1;
  int r0 = blockIdx.x * 64 + wr * 32;
  int c0 = yt * 64 + wc * 32;
  if (c0 >= 160) return;
  int lr = lane & 15;
  int ko = (lane >> 4) * 8;
  const unsigned short* Ap0 = A + (size_t)(r0 + lr) * 160 + ko;
  const unsigned short* Ap1 = Ap0 + (size_t)16 * 160;
  const unsigned short* Wp0 = W + (size_t)(c0 + lr) * 160 + ko;
  const unsigned short* Wp1 = Wp0 + (size_t)16 * 160;
  f32x4 acc00 = {0, 0, 0, 0}, acc01 = {0, 0, 0, 0};
  f32x4 acc10 = {0, 0, 0, 0}, acc11 = {0, 0, 0, 0};
#pragma unroll
  for (int k = 0; k < 160; k += 32) {
    bf16x8 a0 = *(const bf16x8*)(Ap0 + k);
    bf16x8 a1 = *(const bf16x8*)(Ap1 + k);
    bf16x8 b0 = *(const bf16x8*)(Wp0 + k);
    bf16x8 b1 = *(const bf16x8*)(Wp1 + k);
    acc00 = __builtin_amdgcn_mfma_f32_16x16x32_bf16(a0, b0, acc00, 0, 0, 0);
    acc01 = __builtin_amdgcn_mfma_f32_16x16x32_bf16(a0, b1, acc01, 0, 0, 0);
    acc10 = __builtin_amdgcn_mfma_f32_16x16x32_bf16(a1, b0, acc10, 0, 0, 0);
    acc11 = __builtin_amdgcn_mfma_f32_16x16x32_bf16(a1, b1, acc11, 0, 0, 0);
  }
  int cA = c0 + lr, cB = c0 + 16 + lr;
  float bc0 = bias[cA];
  float bc1 = bias[cB];
  int pcA = (cA / 20) * 32 + cA % 20;
  int pcB = (cB / 20) * 32 + cB % 20;
  int rb = (lane >> 4) * 4;
  if (which < 2) {
    unsigned short* out = which ? Kp : Qp;
#pragma unroll
    for (int i = 0; i < 2; ++i) {
      f32x4 aA = i ? acc10 : acc00;
      f32x4 aB = i ? acc11 : acc01;
#pragma unroll
      for (int r = 0; r < 4; ++r) {
        int row = r0 + i * 16 + rb + r;
        out[(size_t)row * 256 + pcA] = f2bf(aA[r] + bc0);
        out[(size_t)row * 256 + pcB] = f2bf(aB[r] + bc1);
      }
    }
  } else {
    int b = r0 >> 10;
    int base32 = r0 & 1023;  // multiple of 32
    size_t colA = ((size_t)b * 256 + pcA) * 1024 + base32;
    size_t colB = ((size_t)b * 256 + pcB) * 1024 + base32;
#pragma unroll
    for (int i = 0; i < 2; ++i) {
      f32x4 aA = i ? acc10 : acc00;
      f32x4 aB = i ? acc11 : acc01;
#pragma unroll
      for (int j = 0; j < 4; ++j) {
        int pos = 2 * (rb + j) + i;  // permuted token slot
        vTp[colA + pos] = f2bf(aA[j] + bc0);
        vTp[colB + pos] = f2bf(aB[j] + bc1);
      }
    }
  }
}

// ---------------- GEMM: out[M,N] = A[M,K] @ W[N,K]^T + bias ----------------
// EPI 1: bias+res->f32   EPI 2: bias+gelu->bf16
template <int EPI>
__global__ void gemm_kernel(const unsigned short* __restrict__ A,
                            const unsigned short* __restrict__ W,
                            const float* __restrict__ bias,
                            const float* __restrict__ res,
                            void* __restrict__ outp, int N, int K) {
  int lane = threadIdx.x & 63;
  int wid = threadIdx.x >> 6;
  int wr = wid >> 1, wc = wid & 1;
  int r0 = blockIdx.x * 64 + wr * 32;
  int c0 = blockIdx.y * 64 + wc * 32;
  if (c0 >= N) return;
  int lr = lane & 15;
  int ko = (lane >> 4) * 8;
  const unsigned short* Ap0 = A + (size_t)(r0 + lr) * K + ko;
  const unsigned short* Ap1 = Ap0 + (size_t)16 * K;
  const unsigned short* Wp0 = W + (size_t)(c0 + lr) * K + ko;
  const unsigned short* Wp1 = Wp0 + (size_t)16 * K;
  f32x4 acc00 = {0, 0, 0, 0}, acc01 = {0, 0, 0, 0};
  f32x4 acc10 = {0, 0, 0, 0}, acc11 = {0, 0, 0, 0};
  for (int k = 0; k < K; k += 32) {
    bf16x8 a0 = *(const bf16x8*)(Ap0 + k);
    bf16x8 a1 = *(const bf16x8*)(Ap1 + k);
    bf16x8 b0 = *(const bf16x8*)(Wp0 + k);
    bf16x8 b1 = *(const bf16x8*)(Wp1 + k);
    acc00 = __builtin_amdgcn_mfma_f32_16x16x32_bf16(a0, b0, acc00, 0, 0, 0);
    acc01 = __builtin_amdgcn_mfma_f32_16x16x32_bf16(a0, b1, acc01, 0, 0, 0);
    acc10 = __builtin_amdgcn_mfma_f32_16x16x32_bf16(a1, b0, acc10, 0, 0, 0);
    acc11 = __builtin_amdgcn_mfma_f32_16x16x32_bf16(a1, b1, acc11, 0, 0, 0);
  }
  int cA = c0 + lr, cB = c0 + 16 + lr;
  float bc0 = bias[cA];
  float bc1 = bias[cB];
  int rb = (lane >> 4) * 4;
#pragma unroll
  for (int i = 0; i < 2; ++i) {
    f32x4 aA = i ? acc10 : acc00;
    f32x4 aB = i ? acc11 : acc01;
#pragma unroll
    for (int r = 0; r < 4; ++r) {
      int row = r0 + i * 16 + rb + r;
      float v0 = aA[r] + bc0;
      float v1 = aB[r] + bc1;
      if (EPI == 2) {
        v0 = 0.5f * v0 * (1.0f + erff(v0 * 0.70710678118654752f));
        v1 = 0.5f * v1 * (1.0f + erff(v1 * 0.70710678118654752f));
        unsigned short* out = (unsigned short*)outp;
        out[(size_t)row * N + cA] = f2bf(v0);
        out[(size_t)row * N + cB] = f2bf(v1);
      } else {
        float* out = (float*)outp;
        out[(size_t)row * N + cA] = v0 + res[(size_t)row * N + cA];
        out[(size_t)row * N + cB] = v1 + res[(size_t)row * N + cB];
      }
    }
  }
}

// ---------------- flash attention, head-padded, KVBLK=64 ------------
// Qp,Kp: [b*1024+tok][256]; vTp: [(b*256+h*32+d)][1024] token-permuted.
// grid: (B*NH, LQ/64)  -- bh on x so one head's q-blocks share an XCD.
__global__ void attn_kernel(const unsigned short* __restrict__ Qp,
                            const unsigned short* __restrict__ Kp,
                            const unsigned short* __restrict__ vTp,
                            unsigned short* __restrict__ O,
                            const float* __restrict__ tau_ptr,
                            float base_scale) {
  __shared__ unsigned short plds[4][16 * PSTR];
  int lane = threadIdx.x & 63;
  int wid = threadIdx.x >> 6;
  int bh = blockIdx.x;
  int b = bh >> 3, h = bh & 7;
  int q0 = blockIdx.y * 64 + wid * 16;
  float sc = base_scale;
  if (tau_ptr) {
    float lt = tau_ptr[0];
    float sp = (lt > 20.0f) ? lt : log1pf(expf(lt));
    sc /= fminf(sp + 0.5f, 2.0f);
  }
  float scale = sc * 1.4426950408889634f;  // log2 domain
  int lr = lane & 15;
  int g = lane >> 4;
  int ko = g * 8;
  int rb = g * 4;
  const size_t tb = (size_t)b * LQN;
  bf16x8 aq = *(const bf16x8*)(Qp + (tb + q0 + lr) * 256 + h * 32 + ko);
  const unsigned short* kr0 = Kp + (tb + lr) * 256 + h * 32 + ko;
  const unsigned short* kr = kr0;
  const unsigned short* vr0 = vTp + ((size_t)b * 256 + h * 32 + lr) * LKN + ko;
  const unsigned short* vr1 = vr0 + (size_t)16 * LKN;
  unsigned short* pwr = plds[wid] + rb * PSTR + 2 * lr;        // u32 writes
  const unsigned short* pra = plds[wid] + lr * PSTR + ko;      // b128 reads
  f32x4 o0 = {0, 0, 0, 0}, o1 = {0, 0, 0, 0};
  float mrow[4], lsum[4];
#pragma unroll
  for (int r = 0; r < 4; ++r) { mrow[r] = -3.0e38f; lsum[r] = 0.0f; }
  const f32x4 zero = {0, 0, 0, 0};
  bf16x8 ck0 = *(const bf16x8*)(kr);
  bf16x8 ck1 = *(const bf16x8*)(kr + 16 * 256);
  bf16x8 ck2 = *(const bf16x8*)(kr + 32 * 256);
  bf16x8 ck3 = *(const bf16x8*)(kr + 48 * 256);
  for (int kt = 0; kt < LKN; kt += 64) {
    f32x4 s0 = __builtin_amdgcn_mfma_f32_16x16x32_bf16(aq, ck0, zero, 0, 0, 0);
    f32x4 s1 = __builtin_amdgcn_mfma_f32_16x16x32_bf16(aq, ck1, zero, 0, 0, 0);
    f32x4 s2 = __builtin_amdgcn_mfma_f32_16x16x32_bf16(aq, ck2, zero, 0, 0, 0);
    f32x4 s3 = __builtin_amdgcn_mfma_f32_16x16x32_bf16(aq, ck3, zero, 0, 0, 0);
    kr = (kt + 64 < LKN) ? kr + 64 * 256 : kr0;
    ck0 = *(const bf16x8*)(kr);
    ck1 = *(const bf16x8*)(kr + 16 * 256);
    ck2 = *(const bf16x8*)(kr + 32 * 256);
    ck3 = *(const bf16x8*)(kr + 48 * 256);
    bf16x8 vb00 = *(const bf16x8*)(vr0 + kt + ko);
    bf16x8 vb01 = *(const bf16x8*)(vr0 + kt + 32 + ko);
    bf16x8 vb10 = *(const bf16x8*)(vr1 + kt + ko);
    bf16x8 vb11 = *(const bf16x8*)(vr1 + kt + 32 + ko);
#pragma unroll
    for (int r = 0; r < 4; ++r) {
      float tm = fmaxf(fmaxf(s0[r], s1[r]), fmaxf(s2[r], s3[r]));
      tm = red16_max(tm);
      float mnew = fmaxf(mrow[r], tm * scale);
      float fac = ex2(mrow[r] - mnew);
      float p0 = ex2(fmaf(s0[r], scale, -mnew));
      float p1 = ex2(fmaf(s1[r], scale, -mnew));
      float p2 = ex2(fmaf(s2[r], scale, -mnew));
      float p3 = ex2(fmaf(s3[r], scale, -mnew));
      float rs = red16_add((p0 + p1) + (p2 + p3));
      lsum[r] = lsum[r] * fac + rs;
      o0[r] *= fac; o1[r] *= fac;
      mrow[r] = mnew;
      // interleaved-k packed store: slots (2*lr, 2*lr+1) <- (k, k+16)
      *(unsigned int*)(pwr + r * PSTR)      = cvtpk(p0, p1);
      *(unsigned int*)(pwr + r * PSTR + 32) = cvtpk(p2, p3);
    }
    bf16x8 pa0 = *(const bf16x8*)(pra);
    bf16x8 pa1 = *(const bf16x8*)(pra + 32);
    o0 = __builtin_amdgcn_mfma_f32_16x16x32_bf16(pa0, vb00, o0, 0, 0, 0);
    o0 = __builtin_amdgcn_mfma_f32_16x16x32_bf16(pa1, vb01, o0, 0, 0, 0);
    o1 = __builtin_amdgcn_mfma_f32_16x16x32_bf16(pa0, vb10, o1, 0, 0, 0);
    o1 = __builtin_amdgcn_mfma_f32_16x16x32_bf16(pa1, vb11, o1, 0, 0, 0);
  }
  unsigned short* ob = O + (tb + q0) * DM + h * HDIM;
#pragma unroll
  for (int r = 0; r < 4; ++r) {
    int qr = rb + r;
    float inv = 1.0f / lsum[r];
    ob[(size_t)qr * DM + lr] = f2bf(o0[r] * inv);
    if (lr < 4) ob[(size_t)qr * DM + 16 + lr] = f2bf(o1[r] * inv);
  }
}

extern "C" void kernel_launch(void* const* d_in, const int* in_sizes, int n_in,
                              void* d_out, int out_size, void* d_ws, size_t ws_size,
                              hipStream_t stream) {
  (void)in_sizes; (void)n_in; (void)out_size; (void)ws_size;
  const float* q        = (const float*)d_in[0];
  const float* kv       = (const float*)d_in[1];
  const float* ln1_g    = (const float*)d_in[2];
  const float* ln1_b    = (const float*)d_in[3];
  const float* sa_in_w  = (const float*)d_in[4];
  const float* sa_in_b  = (const float*)d_in[5];
  const float* sa_out_w = (const float*)d_in[6];
  const float* sa_out_b = (const float*)d_in[7];
  const float* ln2_g    = (const float*)d_in[8];
  const float* ln2_b    = (const float*)d_in[9];
  const float* lnkv_g   = (const float*)d_in[10];
  const float* lnkv_b   = (const float*)d_in[11];
  const float* ca_qw    = (const float*)d_in[12];
  const float* ca_qb    = (const float*)d_in[13];
  const float* ca_kw    = (const float*)d_in[14];
  const float* ca_kb    = (const float*)d_in[15];
  const float* ca_vw    = (const float*)d_in[16];
  const float* ca_vb    = (const float*)d_in[17];
  const float* ca_ow    = (const float*)d_in[18];
  const float* ca_ob    = (const float*)d_in[19];
  const float* log_tau  = (const float*)d_in[20];
  const float* lnf_g    = (const float*)d_in[21];
  const float* lnf_b    = (const float*)d_in[22];
  const float* w1       = (const float*)d_in[23];
  const float* b1       = (const float*)d_in[24];
  const float* w2       = (const float*)d_in[25];
  const float* b2       = (const float*)d_in[26];

  const int M = NB * LQN;  // 16384 rows
  char* ws = (char*)d_ws;
  unsigned short* wb   = (unsigned short*)(ws);
  unsigned short* qn   = (unsigned short*)(ws + 1048576);
  unsigned short* sqp  = (unsigned short*)(ws + 6291456);
  unsigned short* skp  = (unsigned short*)(ws + 14680064);
  unsigned short* vTp  = (unsigned short*)(ws + 23068672);
  unsigned short* attn = (unsigned short*)(ws + 31457280);
  unsigned short* kvn  = (unsigned short*)(ws + 36700160);
  float*          q1   = (float*)(ws + 41943040);
  float*          q2   = (float*)(ws + 52428800);
  unsigned short* hbuf = (unsigned short*)(ws + 6291456);  // FFN phase reuse

  unsigned short* b_sa_in  = wb;            // 76800
  unsigned short* b_sa_out = wb + 76800;    // 25600
  unsigned short* b_ca_q   = wb + 102400;   // 25600
  unsigned short* b_ca_k   = wb + 128000;   // 25600
  unsigned short* b_ca_v   = wb + 153600;   // 25600
  unsigned short* b_ca_o   = wb + 179200;   // 25600
  unsigned short* b_w1     = wb + 204800;   // 102400
  unsigned short* b_w2     = wb + 307200;   // 102400

  dim3 blk(256);
  const float isq = 0.22360679774997896f;  // 1/sqrt(20)

  // --- zero the padded buffers ---
  zero_kernel<<<dim3(6144), blk, 0, stream>>>((uint4*)(ws + 6291456), 1572864);

  // --- weight conversion, one launch ---
  CvtArgs ca;
  ca.src[0] = sa_in_w;  ca.src[1] = sa_out_w; ca.src[2] = ca_qw; ca.src[3] = ca_kw;
  ca.src[4] = ca_vw;    ca.src[5] = ca_ow;    ca.src[6] = w1;    ca.src[7] = w2;
  int cum[9] = {0, 76800, 102400, 128000, 153600, 179200, 204800, 307200, 409600};
  for (int i = 0; i < 9; ++i) ca.cum[i] = cum[i];
  cvt8_kernel<<<dim3(1600), blk, 0, stream>>>(ca, wb);

  // --- self attention block ---
  ln_kernel<<<dim3(M / 4), blk, 0, stream>>>(q, ln1_g, ln1_b, qn, M);
  qkv_kernel<<<dim3(M / 64, 9), blk, 0, stream>>>(
      qn, qn, b_sa_in, b_sa_in + 160 * 160, b_sa_in + 320 * 160,
      sa_in_b, sa_in_b + 160, sa_in_b + 320, sqp, skp, vTp);
  attn_kernel<<<dim3(NB * NHEADS, LQN / 64), blk, 0, stream>>>(sqp, skp, vTp, attn, nullptr, isq);
  gemm_kernel<1><<<dim3(M / 64, 3), blk, 0, stream>>>(attn, b_sa_out, sa_out_b, q, q1, 160, 160);

  // --- cross attention block ---
  ln_kernel<<<dim3(M / 4), blk, 0, stream>>>(q1, ln2_g, ln2_b, qn, M);
  ln_kernel<<<dim3(M / 4), blk, 0, stream>>>(kv, lnkv_g, lnkv_b, kvn, M);
  qkv_kernel<<<dim3(M / 64, 9), blk, 0, stream>>>(
      qn, kvn, b_ca_q, b_ca_k, b_ca_v,
      ca_qb, ca_kb, ca_vb, sqp, skp, vTp);
  attn_kernel<<<dim3(NB * NHEADS, LQN / 64), blk, 0, stream>>>(sqp, skp, vTp, attn, log_tau, isq);
  gemm_kernel<1><<<dim3(M / 64, 3), blk, 0, stream>>>(attn, b_ca_o, ca_ob, q1, q2, 160, 160);

  // --- FFN ---
  ln_kernel<<<dim3(M / 4), blk, 0, stream>>>(q2, lnf_g, lnf_b, qn, M);
  gemm_kernel<2><<<dim3(M / 64, 10), blk, 0, stream>>>(qn, b_w1, b1, nullptr, hbuf, 640, 160);
  gemm_kernel<1><<<dim3(M / 64, 3), blk, 0, stream>>>(hbuf, b_w2, b2, q2, (float*)d_out, 160, 640);
}